// Round 17
// baseline (109.977 us; speedup 1.0000x reference)
//
#include <hip/hip_runtime.h>
#include <hip/hip_bf16.h>

#define N_NODES 256
#define BATCH   1024
#define NI      8     // node indices per block (producer/consumer pipeline)
#define ROWB    528   // padded LDS row stride (bytes), imm-offset addressing
#define CSC     2.8853900817779268f   // 2*log2(e): tanh(x)=1-2/(exp2(c*x)+1)

typedef __attribute__((ext_vector_type(8))) short bf16x8;
typedef __attribute__((ext_vector_type(4))) float f32x4;
typedef __attribute__((ext_vector_type(2))) float f32x2;

__device__ __forceinline__ float ftanh(float x) {
    // full tanh for prep/final (input NOT prescaled)
    float e = __builtin_amdgcn_exp2f(x * CSC);
    float r = __builtin_amdgcn_rcpf(e + 1.0f);
    return fmaf(-2.0f, r, 1.0f);
}

__device__ __forceinline__ unsigned short f2bf(float f) {
    unsigned u = __float_as_uint(f);
    return (unsigned short)((u + 0x7fffu + ((u >> 16) & 1u)) >> 16);
}

__device__ __forceinline__ unsigned pack_bf2(float a, float b) {
    union { __hip_bfloat162 h; unsigned u; } cvt;
    cvt.h = __float22bfloat162_rn(make_float2(a, b));
    return cvt.u;
}

__device__ __forceinline__ f32x2 pkfma(f32x2 a, f32x2 b, f32x2 c) {
    return __builtin_elementwise_fma(a, b, c);   // -> v_pk_fma_f32
}

// tanh on a PRESCALED pair d2 = c*x: exp2 x2, pk_add, rcp x2, pk_fma.
__device__ __forceinline__ f32x2 tanh2_pre(f32x2 d2) {
    f32x2 e2;
    e2.x = __builtin_amdgcn_exp2f(d2.x);
    e2.y = __builtin_amdgcn_exp2f(d2.y);
    e2 = e2 + 1.0f;                               // v_pk_add_f32
    f32x2 r2;
    r2.x = __builtin_amdgcn_rcpf(e2.x);
    r2.y = __builtin_amdgcn_rcpf(e2.y);
    return pkfma((f32x2){-2.f, -2.f}, r2, (f32x2){1.f, 1.f});
}

// DPP row_shr reduce; 16-lane sum lands in lane 15 (round-6 post-mortem).
template <int CTRL>
__device__ __forceinline__ float dpp_add(float s) {
    int t = __builtin_amdgcn_update_dpp(0, __float_as_int(s), CTRL, 0xf, 0xf, true);
    return s + __int_as_float(t);
}

// ------- P1: Z0c = c*(x @ W0^T) + prep (all weights prescaled by c) -------
__global__ void z0_prep(const float* __restrict__ x, const float* __restrict__ W0,
                        const float* __restrict__ W1, float* __restrict__ Z0c,
                        float* __restrict__ xT, float* __restrict__ W0c,
                        unsigned short* __restrict__ W1bf) {
    __shared__ float xs[32][36];
    __shared__ float ws[32][36];
    int t = threadIdx.x;

    int gb = (blockIdx.y * 32 + blockIdx.x) * 256 + t;
    {
        int i = gb >> 8, m = gb & 255;
        W0c[gb]  = W0[m * 256 + i] * CSC;     // W0c[i*256+m] = c*W0[m][i]
        W1bf[gb] = f2bf(W1[gb] * CSC);        // c*W1 (bf16): MFMA yields c*z1
    }
#pragma unroll
    for (int r = 0; r < 4; ++r) {
        int id = r * 65536 + gb;
        int i = id >> 10, b = id & 1023;
        xT[id] = x[b * 256 + i];
    }

    int b0 = blockIdx.x * 32, m0 = blockIdx.y * 32;
    int lr = t >> 3, lc = (t & 7) << 2;
    int tr = (t >> 4) << 1, tc = (t & 15) << 1;
    float acc00 = 0.f, acc01 = 0.f, acc10 = 0.f, acc11 = 0.f;
    for (int k0 = 0; k0 < 256; k0 += 32) {
        *(float4*)&xs[lr][lc] = *(const float4*)&x[(b0 + lr) * 256 + k0 + lc];
        *(float4*)&ws[lr][lc] = *(const float4*)&W0[(m0 + lr) * 256 + k0 + lc];
        __syncthreads();
#pragma unroll
        for (int k = 0; k < 32; ++k) {
            float a0 = xs[tr][k], a1 = xs[tr + 1][k];
            float w0v = ws[tc][k], w1v = ws[tc + 1][k];
            acc00 = fmaf(a0, w0v, acc00);
            acc01 = fmaf(a0, w1v, acc01);
            acc10 = fmaf(a1, w0v, acc10);
            acc11 = fmaf(a1, w1v, acc11);
        }
        __syncthreads();
    }
    Z0c[(b0 + tr) * 256 + m0 + tc]         = acc00 * CSC;
    Z0c[(b0 + tr) * 256 + m0 + tc + 1]     = acc01 * CSC;
    Z0c[(b0 + tr + 1) * 256 + m0 + tc]     = acc10 * CSC;
    Z0c[(b0 + tr + 1) * 256 + m0 + tc + 1] = acc11 * CSC;
}

// ---------------- F: producer/consumer specialized fused kernel -----------
// 8 waves: 0-3 consume (MFMA+phase2 for i), 4-7 produce (phase0 tanh for i+1
// into the other h0 buffer). Breaks the phase convoy: every CU always holds
// both MFMA-heavy and VALU-heavy waves (m114: they overlap, time = max).
__launch_bounds__(512, 2)
__global__ void fused(const float* __restrict__ Z0c, const float* __restrict__ xT,
                      const float* __restrict__ W0c,
                      const unsigned short* __restrict__ W1bf,
                      const float* __restrict__ W2, float* __restrict__ out) {
    __shared__ __align__(16) unsigned char h0buf[2][64 * ROWB]; // 2 x 33 KiB
    __shared__ float wavepart[2][4 * 64];                        // 2 x 1 KiB
    const int t  = threadIdx.x;
    const int r0 = blockIdx.x * 64;   // batch tile base
    const int i0 = blockIdx.y * NI;   // node chunk base
    const int wid = t >> 6;

    if (wid >= 4) {
        // ============ producers: build h0(i0) into buf 0 (prologue) =======
        const int pt = t & 255;
        const int rowgrp = pt >> 5, chunk = pt & 31, col0 = chunk << 3;
        unsigned char* wbase = h0buf[0] + rowgrp * ROWB + chunk * 16;
        float4 w0a = *(const float4*)&W0c[i0 * 256 + col0];
        float4 w0b = *(const float4*)&W0c[i0 * 256 + col0 + 4];
        f32x2 wv[4] = {(f32x2){w0a.x, w0a.y}, (f32x2){w0a.z, w0a.w},
                       (f32x2){w0b.x, w0b.y}, (f32x2){w0b.z, w0b.w}};
#pragma unroll
        for (int p = 0; p < 8; ++p) {
            int row = p * 8 + rowgrp;
            float xi = xT[i0 * 1024 + r0 + row];
            f32x2 nxi = (f32x2){-xi, -xi};
            float4 za = *(const float4*)&Z0c[(r0 + row) * 256 + col0];
            float4 zb = *(const float4*)&Z0c[(r0 + row) * 256 + col0 + 4];
            f32x2 zv[4] = {(f32x2){za.x, za.y}, (f32x2){za.z, za.w},
                           (f32x2){zb.x, zb.y}, (f32x2){zb.z, zb.w}};
            unsigned pk[4];
#pragma unroll
            for (int e = 0; e < 4; ++e) {
                f32x2 h = tanh2_pre(pkfma(nxi, wv[e], zv[e]));
                pk[e] = pack_bf2(h.x, h.y);
            }
            *(uint4*)(wbase + p * 8 * ROWB) = make_uint4(pk[0], pk[1], pk[2], pk[3]);
        }
    }
    __syncthreads();

    for (int k = 0; k < NI; ++k) {
        const int i = i0 + k;
        if (wid < 4) {
            // ============ consumers: MFMA(i) on buf[k&1] + phase2 =========
            const int lane = t & 63, lr = lane & 15, lh = lane >> 4;
            float w2v[4];
#pragma unroll
            for (int nt = 0; nt < 4; ++nt)
                w2v[nt] = W2[i * 256 + wid * 64 + nt * 16 + lr];

            f32x4 acc[4][4];
#pragma unroll
            for (int a = 0; a < 4; ++a)
#pragma unroll
                for (int b = 0; b < 4; ++b)
                    acc[a][b] = (f32x4){0.f, 0.f, 0.f, 0.f};

            const unsigned char* abase[4];
#pragma unroll
            for (int mt = 0; mt < 4; ++mt)
                abase[mt] = h0buf[k & 1] + (mt * 16 + lr) * ROWB + lh * 16;

            const unsigned short* w1p[4];
#pragma unroll
            for (int nt = 0; nt < 4; ++nt)
                w1p[nt] = W1bf + (wid * 64 + nt * 16 + lr) * 256 + lh * 8;
            bf16x8 bnext[4];
#pragma unroll
            for (int nt = 0; nt < 4; ++nt)
                bnext[nt] = *(const bf16x8*)(w1p[nt]);

#pragma unroll
            for (int ks = 0; ks < 8; ++ks) {
                bf16x8 bfrag[4];
#pragma unroll
                for (int nt = 0; nt < 4; ++nt) {
                    bfrag[nt] = bnext[nt];
                    if (ks < 7)
                        bnext[nt] = *(const bf16x8*)(w1p[nt] + (ks + 1) * 32);
                }
                bf16x8 afrag[4];
#pragma unroll
                for (int mt = 0; mt < 4; ++mt)
                    afrag[mt] = *(const bf16x8*)(abase[mt] + ks * 64);
#pragma unroll
                for (int mt = 0; mt < 4; ++mt)
#pragma unroll
                    for (int nt = 0; nt < 4; ++nt)
                        acc[mt][nt] = __builtin_amdgcn_mfma_f32_16x16x32_bf16(
                            afrag[mt], bfrag[nt], acc[mt][nt], 0, 0, 0);
            }

            // phase 2: packed tanh on c-scaled acc; dot W2; DPP reduce
#pragma unroll
            for (int mt = 0; mt < 4; ++mt) {
#pragma unroll
                for (int p = 0; p < 2; ++p) {
                    f32x2 s2 = (f32x2){0.f, 0.f};
#pragma unroll
                    for (int nt = 0; nt < 4; ++nt) {
                        f32x2 zc = (f32x2){acc[mt][nt][2 * p], acc[mt][nt][2 * p + 1]};
                        f32x2 h2 = tanh2_pre(zc);
                        s2 = pkfma(h2, (f32x2){w2v[nt], w2v[nt]}, s2);
                    }
#pragma unroll
                    for (int q = 0; q < 2; ++q) {
                        float s = s2[q];
                        s = dpp_add<0x118>(s);
                        s = dpp_add<0x114>(s);
                        s = dpp_add<0x112>(s);
                        s = dpp_add<0x111>(s);   // sum at lane 15
                        if (lr == 15)
                            wavepart[k & 1][wid * 64 + mt * 16 + lh * 4 + 2 * p + q] = s;
                    }
                }
            }
        } else {
            // ============ producers: build h0(i+1) into buf[(k+1)&1] ======
            if (k + 1 < NI) {
                const int inx = i + 1;
                const int pt = t & 255;
                const int rowgrp = pt >> 5, chunk = pt & 31, col0 = chunk << 3;
                unsigned char* wbase = h0buf[(k + 1) & 1] + rowgrp * ROWB + chunk * 16;
                float4 w0a = *(const float4*)&W0c[inx * 256 + col0];
                float4 w0b = *(const float4*)&W0c[inx * 256 + col0 + 4];
                f32x2 wv[4] = {(f32x2){w0a.x, w0a.y}, (f32x2){w0a.z, w0a.w},
                               (f32x2){w0b.x, w0b.y}, (f32x2){w0b.z, w0b.w}};
#pragma unroll
                for (int p = 0; p < 8; ++p) {
                    int row = p * 8 + rowgrp;
                    float xi = xT[inx * 1024 + r0 + row];
                    f32x2 nxi = (f32x2){-xi, -xi};
                    float4 za = *(const float4*)&Z0c[(r0 + row) * 256 + col0];
                    float4 zb = *(const float4*)&Z0c[(r0 + row) * 256 + col0 + 4];
                    f32x2 zv[4] = {(f32x2){za.x, za.y}, (f32x2){za.z, za.w},
                                   (f32x2){zb.x, zb.y}, (f32x2){zb.z, zb.w}};
                    unsigned pk[4];
#pragma unroll
                    for (int e = 0; e < 4; ++e) {
                        f32x2 h = tanh2_pre(pkfma(nxi, wv[e], zv[e]));
                        pk[e] = pack_bf2(h.x, h.y);
                    }
                    *(uint4*)(wbase + p * 8 * ROWB) =
                        make_uint4(pk[0], pk[1], pk[2], pk[3]);
                }
            }
            // phase 3 for i-1 (wave 4, lanes 0-63): wavepart[(k-1)&1]
            if (k > 0 && t < 320) {
                const int l = t - 256;
                const float* wp = wavepart[(k + 1) & 1];
                float s = wp[l] + wp[64 + l] + wp[128 + l] + wp[192 + l];
                out[(r0 + l) * 256 + (i - 1)] = ftanh(s);
            }
        }
        __syncthreads();
    }

    // epilogue: phase 3 for the last i
    if (t >= 256 && t < 320) {
        const int l = t - 256;
        const float* wp = wavepart[(NI - 1) & 1];
        float s = wp[l] + wp[64 + l] + wp[128 + l] + wp[192 + l];
        out[(r0 + l) * 256 + (i0 + NI - 1)] = ftanh(s);
    }
}

extern "C" void kernel_launch(void* const* d_in, const int* in_sizes, int n_in,
                              void* d_out, int out_size, void* d_ws, size_t ws_size,
                              hipStream_t stream) {
    const float* x  = (const float*)d_in[0];
    const float* W0 = (const float*)d_in[1];
    const float* W1 = (const float*)d_in[2];
    const float* W2 = (const float*)d_in[3];
    float* out = (float*)d_out;

    char* ws = (char*)d_ws;
    float* Z0c           = (float*)ws;                               // 1 MB
    float* xT            = (float*)(ws + (1 << 20));                 // 1 MB
    float* W0c           = (float*)(ws + (2 << 20));                 // 256 KB
    unsigned short* W1bf = (unsigned short*)(ws + (2 << 20) + (256 << 10)); // 128 KB

    z0_prep<<<dim3(32, 8), 256, 0, stream>>>(x, W0, W1, Z0c, xT, W0c, W1bf);
    fused<<<dim3(16, 256 / NI), 512, 0, stream>>>(Z0c, xT, W0c, W1bf, W2, out);
}

// Round 18
// 88.606 us; speedup vs baseline: 1.2412x; 1.2412x over previous
//
#include <hip/hip_runtime.h>
#include <hip/hip_bf16.h>

#define N_NODES 256
#define BATCH   1024
#define CSC     2.8853900817779268f   // 2*log2(e): tanh(x)=1-2/(exp2(c*x)+1)

typedef __attribute__((ext_vector_type(8))) short bf16x8;
typedef __attribute__((ext_vector_type(4))) float f32x4;
typedef __attribute__((ext_vector_type(2))) float f32x2;

__device__ __forceinline__ float ftanh(float x) {
    float e = __builtin_amdgcn_exp2f(x * CSC);
    float r = __builtin_amdgcn_rcpf(e + 1.0f);
    return fmaf(-2.0f, r, 1.0f);
}

__device__ __forceinline__ unsigned short f2bf(float f) {
    unsigned u = __float_as_uint(f);
    return (unsigned short)((u + 0x7fffu + ((u >> 16) & 1u)) >> 16);
}

__device__ __forceinline__ unsigned pack_bf2(float a, float b) {
    union { __hip_bfloat162 h; unsigned u; } cvt;
    cvt.h = __float22bfloat162_rn(make_float2(a, b));
    return cvt.u;
}

__device__ __forceinline__ f32x2 pkfma(f32x2 a, f32x2 b, f32x2 c) {
    return __builtin_elementwise_fma(a, b, c);   // -> v_pk_fma_f32
}

// tanh on a PRESCALED pair d2 = c*x: exp2 x2, pk_add, rcp x2, pk_fma.
__device__ __forceinline__ f32x2 tanh2_pre(f32x2 d2) {
    f32x2 e2;
    e2.x = __builtin_amdgcn_exp2f(d2.x);
    e2.y = __builtin_amdgcn_exp2f(d2.y);
    e2 = e2 + 1.0f;
    f32x2 r2;
    r2.x = __builtin_amdgcn_rcpf(e2.x);
    r2.y = __builtin_amdgcn_rcpf(e2.y);
    return pkfma((f32x2){-2.f, -2.f}, r2, (f32x2){1.f, 1.f});
}

// DPP row_shr reduce; 16-lane sum lands in lane 15 (round-6 post-mortem).
template <int CTRL>
__device__ __forceinline__ float dpp_add(float s) {
    int t = __builtin_amdgcn_update_dpp(0, __float_as_int(s), CTRL, 0xf, 0xf, true);
    return s + __int_as_float(t);
}

// ------- P1: Z0c = c*(x @ W0^T) + prep (all weights prescaled by c) -------
__global__ void z0_prep(const float* __restrict__ x, const float* __restrict__ W0,
                        const float* __restrict__ W1, float* __restrict__ Z0c,
                        float* __restrict__ xT, float* __restrict__ W0c,
                        unsigned short* __restrict__ W1bf) {
    __shared__ float xs[32][36];
    __shared__ float ws[32][36];
    int t = threadIdx.x;

    int gb = (blockIdx.y * 32 + blockIdx.x) * 256 + t;
    {
        int i = gb >> 8, m = gb & 255;
        W0c[gb]  = W0[m * 256 + i] * CSC;
        W1bf[gb] = f2bf(W1[gb] * CSC);
    }
#pragma unroll
    for (int r = 0; r < 4; ++r) {
        int id = r * 65536 + gb;
        int i = id >> 10, b = id & 1023;
        xT[id] = x[b * 256 + i];
    }

    int b0 = blockIdx.x * 32, m0 = blockIdx.y * 32;
    int lr = t >> 3, lc = (t & 7) << 2;
    int tr = (t >> 4) << 1, tc = (t & 15) << 1;
    float acc00 = 0.f, acc01 = 0.f, acc10 = 0.f, acc11 = 0.f;
    for (int k0 = 0; k0 < 256; k0 += 32) {
        *(float4*)&xs[lr][lc] = *(const float4*)&x[(b0 + lr) * 256 + k0 + lc];
        *(float4*)&ws[lr][lc] = *(const float4*)&W0[(m0 + lr) * 256 + k0 + lc];
        __syncthreads();
#pragma unroll
        for (int k = 0; k < 32; ++k) {
            float a0 = xs[tr][k], a1 = xs[tr + 1][k];
            float w0v = ws[tc][k], w1v = ws[tc + 1][k];
            acc00 = fmaf(a0, w0v, acc00);
            acc01 = fmaf(a0, w1v, acc01);
            acc10 = fmaf(a1, w0v, acc10);
            acc11 = fmaf(a1, w1v, acc11);
        }
        __syncthreads();
    }
    Z0c[(b0 + tr) * 256 + m0 + tc]         = acc00 * CSC;
    Z0c[(b0 + tr) * 256 + m0 + tc + 1]     = acc01 * CSC;
    Z0c[(b0 + tr + 1) * 256 + m0 + tc]     = acc10 * CSC;
    Z0c[(b0 + tr + 1) * 256 + m0 + tc + 1] = acc11 * CSC;
}

// ---------------- F: R16 frame + full phase-0 load hoisting ---------------
// All phase-0 inputs (16 float4 Z0, 8 xi, 2 float4 W0, first W1 frags) are
// loaded into registers BEFORE any compute: one latency exposure instead of
// ~16 serial ones (R16's VGPR=60 forced serialization). XOR-swizzled 32 KiB
// h0 (0 conflicts, R2-verified) + separate wavepart. bounds (256,3): VGPR
// cap ~168 so the ~80-reg live set fits without spill (R3 tripwire: FETCH).
__launch_bounds__(256, 3)
__global__ void fused(const float* __restrict__ Z0c, const float* __restrict__ xT,
                      const float* __restrict__ W0c,
                      const unsigned short* __restrict__ W1bf,
                      const float* __restrict__ W2, float* __restrict__ out) {
    __shared__ __align__(16) unsigned char h0s[64 * 512];   // 32 KiB, XOR swz
    __shared__ float wavepart[4 * 64];                       // 1 KiB
    const int t  = threadIdx.x;
    const int r0 = blockIdx.x * 64;   // batch tile base
    const int i  = blockIdx.y;        // node index

    const int wave = t >> 6, lane = t & 63;
    const int lr = lane & 15, lh = lane >> 4;

    // ---- hoist ALL independent loads first (single latency exposure) ----
    float w2v[4];
#pragma unroll
    for (int nt = 0; nt < 4; ++nt)
        w2v[nt] = W2[i * 256 + wave * 64 + nt * 16 + lr];

    const unsigned short* w1p[4];
#pragma unroll
    for (int nt = 0; nt < 4; ++nt)
        w1p[nt] = W1bf + (wave * 64 + nt * 16 + lr) * 256 + lh * 8;
    bf16x8 bnext[4];
#pragma unroll
    for (int nt = 0; nt < 4; ++nt)
        bnext[nt] = *(const bf16x8*)(w1p[nt]);

    const int rowgrp = t >> 5, chunk = t & 31, col0 = chunk << 3;
    float4 w0a = *(const float4*)&W0c[i * 256 + col0];
    float4 w0b = *(const float4*)&W0c[i * 256 + col0 + 4];

    float xi[8];
    float4 za[8], zb[8];
#pragma unroll
    for (int p = 0; p < 8; ++p) {
        int row = p * 8 + rowgrp;
        xi[p] = xT[i * 1024 + r0 + row];
        za[p] = *(const float4*)&Z0c[(r0 + row) * 256 + col0];
        zb[p] = *(const float4*)&Z0c[(r0 + row) * 256 + col0 + 4];
    }

    // ---- phase 0: compute + pack + swizzled LDS store (loads all done) --
    {
        f32x2 wv[4] = {(f32x2){w0a.x, w0a.y}, (f32x2){w0a.z, w0a.w},
                       (f32x2){w0b.x, w0b.y}, (f32x2){w0b.z, w0b.w}};
#pragma unroll
        for (int p = 0; p < 8; ++p) {
            int row = p * 8 + rowgrp;
            f32x2 nxi = (f32x2){-xi[p], -xi[p]};
            f32x2 zv[4] = {(f32x2){za[p].x, za[p].y}, (f32x2){za[p].z, za[p].w},
                           (f32x2){zb[p].x, zb[p].y}, (f32x2){zb[p].z, zb[p].w}};
            unsigned pk[4];
#pragma unroll
            for (int e = 0; e < 4; ++e) {
                f32x2 h = tanh2_pre(pkfma(nxi, wv[e], zv[e]));
                pk[e] = pack_bf2(h.x, h.y);
            }
            *(uint4*)(h0s + row * 512 + (((chunk ^ (row & 31)) << 4))) =
                make_uint4(pk[0], pk[1], pk[2], pk[3]);
        }
    }
    __syncthreads();

    // ---- phase 1: c*z1 = h0 @ (c*W1)^T via MFMA (64 rows x 64 cols/wave)
    f32x4 acc[4][4];
#pragma unroll
    for (int a = 0; a < 4; ++a)
#pragma unroll
        for (int b = 0; b < 4; ++b)
            acc[a][b] = (f32x4){0.f, 0.f, 0.f, 0.f};

#pragma unroll
    for (int ks = 0; ks < 8; ++ks) {
        int kchunk = ks * 4 + (lh >> 1);          // 16B chunk idx of kk
        bf16x8 bfrag[4];
#pragma unroll
        for (int nt = 0; nt < 4; ++nt) {
            bfrag[nt] = bnext[nt];
            if (ks < 7)
                bnext[nt] = *(const bf16x8*)(w1p[nt] + (ks + 1) * 32);
        }
        bf16x8 afrag[4];
#pragma unroll
        for (int mt = 0; mt < 4; ++mt) {
            int row = mt * 16 + lr;
            afrag[mt] = *(const bf16x8*)(h0s + row * 512 +
                                         ((kchunk ^ (row & 31)) << 4) +
                                         ((lh & 1) ? 0 : 0));
            // NOTE: kk = ks*32 + lh*8 spans 16 bf16 = one 16B chunk per 2 lh;
            // chunk index = (ks*32 + lh*8)/8 /. .. recompute exactly:
        }
        // exact addressing: chunk = (ks*32 + lh*8) >> 3 ... = ks*4 + lh
        // (8 bf16 = 16 B = one chunk). Redo with correct chunk:
#pragma unroll
        for (int mt = 0; mt < 4; ++mt) {
            int row = mt * 16 + lr;
            int ch2 = ks * 4 + lh;                // 8 bf16 per 16B chunk
            afrag[mt] = *(const bf16x8*)(h0s + row * 512 + ((ch2 ^ (row & 31)) << 4));
        }
#pragma unroll
        for (int mt = 0; mt < 4; ++mt)
#pragma unroll
            for (int nt = 0; nt < 4; ++nt)
                acc[mt][nt] = __builtin_amdgcn_mfma_f32_16x16x32_bf16(
                    afrag[mt], bfrag[nt], acc[mt][nt], 0, 0, 0);
    }

    // ---- phase 2: packed tanh on c-scaled acc; dot W2; DPP reduce -------
#pragma unroll
    for (int mt = 0; mt < 4; ++mt) {
#pragma unroll
        for (int p = 0; p < 2; ++p) {
            f32x2 s2 = (f32x2){0.f, 0.f};
#pragma unroll
            for (int nt = 0; nt < 4; ++nt) {
                f32x2 zc = (f32x2){acc[mt][nt][2 * p], acc[mt][nt][2 * p + 1]};
                f32x2 h2 = tanh2_pre(zc);
                s2 = pkfma(h2, (f32x2){w2v[nt], w2v[nt]}, s2);
            }
#pragma unroll
            for (int q = 0; q < 2; ++q) {
                float s = s2[q];
                s = dpp_add<0x118>(s);
                s = dpp_add<0x114>(s);
                s = dpp_add<0x112>(s);
                s = dpp_add<0x111>(s);   // sum at lane 15
                if (lr == 15)
                    wavepart[wave * 64 + mt * 16 + lh * 4 + 2 * p + q] = s;
            }
        }
    }
    __syncthreads();

    // ---- phase 3: sum 4 wave partials, final tanh (unscaled), store col i
    if (t < 64) {
        float s = wavepart[t] + wavepart[64 + t] + wavepart[128 + t] + wavepart[192 + t];
        out[(r0 + t) * 256 + i] = ftanh(s);
    }
}

extern "C" void kernel_launch(void* const* d_in, const int* in_sizes, int n_in,
                              void* d_out, int out_size, void* d_ws, size_t ws_size,
                              hipStream_t stream) {
    const float* x  = (const float*)d_in[0];
    const float* W0 = (const float*)d_in[1];
    const float* W1 = (const float*)d_in[2];
    const float* W2 = (const float*)d_in[3];
    float* out = (float*)d_out;

    char* ws = (char*)d_ws;
    float* Z0c           = (float*)ws;                               // 1 MB
    float* xT            = (float*)(ws + (1 << 20));                 // 1 MB
    float* W0c           = (float*)(ws + (2 << 20));                 // 256 KB
    unsigned short* W1bf = (unsigned short*)(ws + (2 << 20) + (256 << 10)); // 128 KB

    z0_prep<<<dim3(32, 8), 256, 0, stream>>>(x, W0, W1, Z0c, xT, W0c, W1bf);
    fused<<<dim3(16, 256), 256, 0, stream>>>(Z0c, xT, W0c, W1bf, W2, out);
}